// Round 9
// baseline (918.257 us; speedup 1.0000x reference)
//
#include <hip/hip_runtime.h>
#include <hip/hip_cooperative_groups.h>
#include <math.h>

// GAT 2-layer: N=100000, E=1600000 (+N self loops), F_IN=128, HID=64, HEADS=2,
// OUT_HEADS=1, NUM_CLASS=18, NEG_SLOPE=0.2
// Round 18: launch-gap hypothesis test. R17 algebra: tail (CSR build + node2 +
// l2 + gaps) = 281us but device-time estimates sum to ~100-130us -> suspect
// ~10-15us inter-launch gaps x 10 launches. This round: entire CSR build
// (deg_init/deg_edges/scan1/scan2/scan3/scatter) merged into ONE cooperative
// kernel with grid.sync() phases (1024x256, co-resident). Launches 10 -> 5.
// gemm12 reverted to 256-thread form (76.5us measured; 512-thr was 93.9 --
// occupancy stuck at 17%, VGPR 88->128, worse LDS:FMA ratio).

#define NEG_SLOPE 0.2f
#define STASH_CAP 128

namespace cg = cooperative_groups;

typedef unsigned short ushort_t;

// ---------------- wave reductions (64 lanes) ----------------
__device__ __forceinline__ float wmax(float v) {
    for (int o = 32; o; o >>= 1) v = fmaxf(v, __shfl_xor(v, o));
    return v;
}
__device__ __forceinline__ float wsum(float v) {
    for (int o = 32; o; o >>= 1) v += __shfl_xor(v, o);
    return v;
}

// ---------------- bf16 helpers (RNE) ----------------
__device__ __forceinline__ unsigned bfpack(float a, float b) {
    unsigned ua = __float_as_uint(a);
    unsigned ub = __float_as_uint(b);
    ua = (ua + 0x7fffu + ((ua >> 16) & 1u)) >> 16;
    ub = (ub + 0x7fffu + ((ub >> 16) & 1u)) & 0xffff0000u;
    return ua | ub;
}
__device__ __forceinline__ ushort_t bf16of(float a) {
    unsigned ua = __float_as_uint(a);
    return (ushort_t)((ua + 0x7fffu + ((ua >> 16) & 1u)) >> 16);
}
__device__ __forceinline__ float bflo(unsigned u) { return __uint_as_float(u << 16); }
__device__ __forceinline__ float bfhi(unsigned u) { return __uint_as_float(u & 0xffff0000u); }
__device__ __forceinline__ float bfval(ushort_t u) { return __uint_as_float(((unsigned)u) << 16); }

// ---------------- cooperative CSR build (one kernel, 5 phases) ----------------
// grid = 1024 blocks x 256 thr (co-resident: 4 blocks/CU). Phase bodies are
// verbatim copies of the proven standalone kernels; block-conditional phases
// keep their __syncthreads() legal (conditions are block-uniform).
__global__ __launch_bounds__(256) void k_csr(const int* __restrict__ ei,
                                             int* __restrict__ deg,
                                             int* __restrict__ eofs,
                                             int* __restrict__ rs,
                                             int* __restrict__ bsum,
                                             int* __restrict__ boff,
                                             int* __restrict__ csr,
                                             int N, int E, int Etot, int NB) {
    cg::grid_group grid = cg::this_grid();
    __shared__ int s[256];
    int t = threadIdx.x;
    int gtid = blockIdx.x * 256 + t;
    int gstride = gridDim.x * 256;
    // ---- phase 0: deg = 1 (slot 0 reserved for self loop) ----
    for (int i = gtid; i < N; i += gstride) deg[i] = 1;
    grid.sync();
    // ---- phase 1: degree count + slot assignment ----
    for (int e = gtid; e < E; e += gstride) eofs[e] = atomicAdd(&deg[ei[E + e]], 1);
    grid.sync();
    // ---- phase 2a: block-local scan (blocks 0..NB-1), partials into rs ----
    if ((int)blockIdx.x < NB) {
        int base = blockIdx.x * 1024;
        int i0 = base + t * 4;
        int d0 = (i0 + 0 < N) ? deg[i0 + 0] : 0;
        int d1 = (i0 + 1 < N) ? deg[i0 + 1] : 0;
        int d2 = (i0 + 2 < N) ? deg[i0 + 2] : 0;
        int d3 = (i0 + 3 < N) ? deg[i0 + 3] : 0;
        int s0 = d0, s1 = s0 + d1, s2 = s1 + d2, s3 = s2 + d3;
        int tsum = s3;
        s[t] = tsum;
        __syncthreads();
        for (int off = 1; off < 256; off <<= 1) {
            int v = (t >= off) ? s[t - off] : 0;
            __syncthreads();
            s[t] += v;
            __syncthreads();
        }
        int excl = s[t] - tsum;
        if (i0 + 0 < N) rs[1 + i0 + 0] = excl + s0;
        if (i0 + 1 < N) rs[1 + i0 + 1] = excl + s1;
        if (i0 + 2 < N) rs[1 + i0 + 2] = excl + s2;
        if (i0 + 3 < N) rs[1 + i0 + 3] = excl + s3;
        if (t == 0) bsum[blockIdx.x] = s[255];
    }
    grid.sync();
    // ---- phase 2b: scan of block sums (block 0) ----
    if (blockIdx.x == 0) {
        int orig = (t < NB) ? bsum[t] : 0;
        s[t] = orig;
        __syncthreads();
        for (int off = 1; off < 256; off <<= 1) {
            int v = (t >= off) ? s[t - off] : 0;
            __syncthreads();
            s[t] += v;
            __syncthreads();
        }
        if (t < NB) boff[t] = s[t] - orig;  // exclusive
    }
    grid.sync();
    // ---- phase 2c: add back ----
    for (int i = gtid; i < N; i += gstride) rs[1 + i] += boff[i >> 10];
    if (gtid == 0) rs[0] = 0;
    grid.sync();
    // ---- phase 3: slice-filtered, atomic-free scatter (8 cohorts x 128) ----
    {
        int c = blockIdx.x & 7;
        int pb = blockIdx.x >> 3;
        int tid2 = pb * 256 + t;
        int stride = 128 * 256;
        for (int e = tid2; e < Etot; e += stride) {
            int dst = (e < E) ? ei[E + e] : (e - E);
            if (((dst >> 13) & 7) != c) continue;
            int src, ofs;
            if (e < E) { src = ei[e]; ofs = eofs[e]; } else { src = dst; ofs = 0; }
            csr[rs[dst] + ofs] = src;
        }
    }
}

// ---------------- fused dense front-end, 256 threads (R16 form, 76.5us) ----------------
// phase A: h0 = relu(x @ W0 + b0) kept in LDS (fp32).
// phase B: h1 = h0 @ W1 (bf16 out) + fused att1 dots.
// LDS: [0,8448): al (x tile [64][132]) then al2 (h0 [64][68]);
//      [8448,16640): W0 [128][64] then W1 [64][128]. 66.5KB -> 2 blocks/CU.
__global__ __launch_bounds__(256) void k_gemm12(const float* __restrict__ x,
                                                const float* __restrict__ W0,
                                                const float* __restrict__ b0,
                                                const float* __restrict__ W1,
                                                const float* __restrict__ as_g,
                                                const float* __restrict__ ad_g,
                                                ushort_t* __restrict__ h1b,
                                                float* __restrict__ as1,
                                                float* __restrict__ ad1, int N) {
    __shared__ float smem[16640];
    float* al  = smem;          // phase A x tile
    float* wl  = smem + 8448;   // phase A W0; phase B W1
    float* al2 = smem;          // phase B h0 tile [64][68]
    int t = threadIdx.x;
    int n0 = blockIdx.x * 64;
    // ---- phase A loads ----
    {
        const float4* wg = (const float4*)W0;
        float4* wl4 = (float4*)wl;
#pragma unroll
        for (int i = 0; i < 8; ++i) wl4[t + i * 256] = wg[t + i * 256];
#pragma unroll
        for (int i = 0; i < 8; ++i) {
            int f = t + i * 256;
            int node = f >> 5, q = f & 31;
            int ng = n0 + node; if (ng > N - 1) ng = N - 1;
            float4 v = ((const float4*)x)[(size_t)ng * 32 + q];
            *(float4*)&al[node * 132 + q * 4] = v;
        }
    }
    __syncthreads();
    // ---- phase A compute ----
    int colg = t & 15;   // cols colg*4..+3
    int rowg = t >> 4;   // rows rowg*4..+3
    float4 acc[4];
#pragma unroll
    for (int j = 0; j < 4; ++j) acc[j] = make_float4(0.f, 0.f, 0.f, 0.f);
    for (int k4 = 0; k4 < 128; k4 += 4) {
        float4 w0 = *(float4*)&wl[(k4 + 0) * 64 + colg * 4];
        float4 w1 = *(float4*)&wl[(k4 + 1) * 64 + colg * 4];
        float4 w2 = *(float4*)&wl[(k4 + 2) * 64 + colg * 4];
        float4 w3 = *(float4*)&wl[(k4 + 3) * 64 + colg * 4];
#pragma unroll
        for (int j = 0; j < 4; ++j) {
            float4 a = *(float4*)&al[(rowg * 4 + j) * 132 + k4];
            acc[j].x += a.x * w0.x + a.y * w1.x + a.z * w2.x + a.w * w3.x;
            acc[j].y += a.x * w0.y + a.y * w1.y + a.z * w2.y + a.w * w3.y;
            acc[j].z += a.x * w0.z + a.y * w1.z + a.z * w2.z + a.w * w3.z;
            acc[j].w += a.x * w0.w + a.y * w1.w + a.z * w2.w + a.w * w3.w;
        }
    }
    float4 bb = ((const float4*)b0)[colg];
    float4 h0v[4];
#pragma unroll
    for (int j = 0; j < 4; ++j) {
        h0v[j].x = fmaxf(acc[j].x + bb.x, 0.f);
        h0v[j].y = fmaxf(acc[j].y + bb.y, 0.f);
        h0v[j].z = fmaxf(acc[j].z + bb.z, 0.f);
        h0v[j].w = fmaxf(acc[j].w + bb.w, 0.f);
    }
    __syncthreads();  // all al/wl reads of phase A complete
    // ---- stage h0 to LDS, load W1 ----
#pragma unroll
    for (int j = 0; j < 4; ++j)
        *(float4*)&al2[(rowg * 4 + j) * 68 + colg * 4] = h0v[j];
    {
        const float4* wg1 = (const float4*)W1;
        float4* wl4 = (float4*)wl;
#pragma unroll
        for (int i = 0; i < 8; ++i) wl4[t + i * 256] = wg1[t + i * 256];
    }
    __syncthreads();
    // ---- phase B compute ----
    int colg2 = t & 31;  // cols colg2*4..+3 (head = colg2>=16)
    int rowg2 = t >> 5;  // rows rowg2*8..+7
    float4 acc2[8];
#pragma unroll
    for (int j = 0; j < 8; ++j) acc2[j] = make_float4(0.f, 0.f, 0.f, 0.f);
    for (int k4 = 0; k4 < 64; k4 += 4) {
        float4 w0 = *(float4*)&wl[(k4 + 0) * 128 + colg2 * 4];
        float4 w1 = *(float4*)&wl[(k4 + 1) * 128 + colg2 * 4];
        float4 w2 = *(float4*)&wl[(k4 + 2) * 128 + colg2 * 4];
        float4 w3 = *(float4*)&wl[(k4 + 3) * 128 + colg2 * 4];
#pragma unroll
        for (int j = 0; j < 8; ++j) {
            float4 a = *(float4*)&al2[(rowg2 * 8 + j) * 68 + k4];
            acc2[j].x += a.x * w0.x + a.y * w1.x + a.z * w2.x + a.w * w3.x;
            acc2[j].y += a.x * w0.y + a.y * w1.y + a.z * w2.y + a.w * w3.y;
            acc2[j].z += a.x * w0.z + a.y * w1.z + a.z * w2.z + a.w * w3.z;
            acc2[j].w += a.x * w0.w + a.y * w1.w + a.z * w2.w + a.w * w3.w;
        }
    }
    float4 asv = ((const float4*)as_g)[colg2];
    float4 adv = ((const float4*)ad_g)[colg2];
    float ps[8], pd[8];
#pragma unroll
    for (int j = 0; j < 8; ++j) {
        ps[j] = acc2[j].x * asv.x + acc2[j].y * asv.y + acc2[j].z * asv.z + acc2[j].w * asv.w;
        pd[j] = acc2[j].x * adv.x + acc2[j].y * adv.y + acc2[j].z * adv.z + acc2[j].w * adv.w;
    }
    for (int o = 1; o < 16; o <<= 1) {
#pragma unroll
        for (int j = 0; j < 8; ++j) {
            ps[j] += __shfl_xor(ps[j], o);
            pd[j] += __shfl_xor(pd[j], o);
        }
    }
#pragma unroll
    for (int j = 0; j < 8; ++j) {
        int n = n0 + rowg2 * 8 + j;
        if (n < N) {
            uint2 pr;
            pr.x = bfpack(acc2[j].x, acc2[j].y);
            pr.y = bfpack(acc2[j].z, acc2[j].w);
            ((uint2*)h1b)[(size_t)n * 32 + colg2] = pr;  // 32 uint2 per row
        }
    }
    int lane = t & 63;
    if ((lane & 15) == 0) {
        int head = (lane >> 4) & 1;
#pragma unroll
        for (int j = 0; j < 8; ++j) {
            int n = n0 + rowg2 * 8 + j;
            if (n < N) {
                as1[n * 2 + head] = ps[j];
                ad1[n * 2 + head] = pd[j];
            }
        }
    }
}

// ---- layer-1 fused, v7 (R13): single-pass softmax (deg<=64), rotated pipeline ----
__global__ __launch_bounds__(256) void k_node_l1(const int* __restrict__ rs,
                                                 const int* __restrict__ csr,
                                                 const ushort_t* __restrict__ h1b,
                                                 const float* __restrict__ as1,
                                                 const float* __restrict__ ad1,
                                                 const float* __restrict__ b1,
                                                 unsigned* __restrict__ aggb, int N) {
    __shared__ float2 stashA[4][128];        // [wid][head*64+edge]
    __shared__ float4 stashE[4][STASH_CAP];  // slow path only
    int wid = threadIdx.x >> 6;
    int lane = threadIdx.x & 63;
    int n = (blockIdx.x * 256 + threadIdx.x) >> 6;
    if (n >= N) return;
    int row = rs[n], end = rs[n + 1];
    int deg = end - row;
    float2 adv = ((const float2*)ad1)[n];
    const float2* asp = (const float2*)as1;
    const char* h1base = (const char*)h1b;
    int eg = lane >> 4;                 // 0..3
    int fl = lane & 15;                 // 0..15
    int head_off = (fl >= 8) ? 64 : 0;
    int flbase = fl * 16;               // byte offset within 256B row
    float acc[8] = {0.f, 0.f, 0.f, 0.f, 0.f, 0.f, 0.f, 0.f};
    float inv0, inv1;
    if (deg <= 64) {
        // ---- fast path: single pass ----
        bool act = lane < deg;
        int src = act ? csr[row + lane] : 0;
        float2 av = asp[src];
        float e0 = av.x + adv.x, e1 = av.y + adv.y;
        e0 = e0 > 0.f ? e0 : NEG_SLOPE * e0;
        e1 = e1 > 0.f ? e1 : NEG_SLOPE * e1;
        if (!act) { e0 = -INFINITY; e1 = -INFINITY; }
        float m0 = wmax(e0), m1 = wmax(e1);
        float p0 = act ? __expf(e0 - m0) : 0.f;
        float p1 = act ? __expf(e1 - m1) : 0.f;
        inv0 = __builtin_amdgcn_rcpf(wsum(p0));
        inv1 = __builtin_amdgcn_rcpf(wsum(p1));
        stashA[wid][lane] = make_float2(__int_as_float(src), p0);
        stashA[wid][64 + lane] = make_float2(__int_as_float(src), p1);
        // rotated software pipeline at 8-edge granularity: prefetch j+8's
        // stash pair + gathers before FMAs of j. Pad entries: p=0/src=0.
        int deg8 = (deg + 7) & ~7;
        int b0i = head_off + eg;
        float2 sa0 = stashA[wid][b0i];
        float2 sa1 = stashA[wid][b0i + 4];
        uint4 u0 = *(const uint4*)(h1base + (((unsigned)__float_as_int(sa0.x)) << 8) + flbase);
        uint4 u1 = *(const uint4*)(h1base + (((unsigned)__float_as_int(sa1.x)) << 8) + flbase);
        for (int j = 0; j < deg8; j += 8) {
            int jn = (j + 8 < deg8) ? j + 8 : 0;  // wrap: hot reload, unused
            float2 sb0 = stashA[wid][b0i + jn];
            float2 sb1 = stashA[wid][b0i + jn + 4];
            uint4 v0 = *(const uint4*)(h1base + (((unsigned)__float_as_int(sb0.x)) << 8) + flbase);
            uint4 v1 = *(const uint4*)(h1base + (((unsigned)__float_as_int(sb1.x)) << 8) + flbase);
            float a0 = sa0.y, a1 = sa1.y;
            acc[0] += bflo(u0.x) * a0; acc[1] += bfhi(u0.x) * a0;
            acc[2] += bflo(u0.y) * a0; acc[3] += bfhi(u0.y) * a0;
            acc[4] += bflo(u0.z) * a0; acc[5] += bfhi(u0.z) * a0;
            acc[6] += bflo(u0.w) * a0; acc[7] += bfhi(u0.w) * a0;
            acc[0] += bflo(u1.x) * a1; acc[1] += bfhi(u1.x) * a1;
            acc[2] += bflo(u1.y) * a1; acc[3] += bfhi(u1.y) * a1;
            acc[4] += bflo(u1.z) * a1; acc[5] += bfhi(u1.z) * a1;
            acc[6] += bflo(u1.w) * a1; acc[7] += bfhi(u1.w) * a1;
            sa0 = sb0; sa1 = sb1; u0 = v0; u1 = v1;
        }
    } else {
        // ---- slow path (deg>64; not taken on this input): two-pass ----
        inv0 = 1.f; inv1 = 1.f;  // stash holds normalized alpha
        float m0 = -INFINITY, m1 = -INFINITY, l0 = 0.f, l1 = 0.f;
        for (int base = row; base < end; base += 64) {
            int idx = base + lane;
            bool act = idx < end;
            int src = act ? csr[idx] : 0;
            float2 av = asp[src];
            float e0 = av.x + adv.x, e1 = av.y + adv.y;
            e0 = e0 > 0.f ? e0 : NEG_SLOPE * e0;
            e1 = e1 > 0.f ? e1 : NEG_SLOPE * e1;
            int sidx = idx - row;
            if (act && sidx < STASH_CAP)
                stashE[wid][sidx] = make_float4(__int_as_float(src), e0, e1, 0.f);
            if (!act) { e0 = -INFINITY; e1 = -INFINITY; }
            float m0n = fmaxf(m0, wmax(e0));
            float m1n = fmaxf(m1, wmax(e1));
            float p0 = act ? __expf(e0 - m0n) : 0.f;
            float p1 = act ? __expf(e1 - m1n) : 0.f;
            l0 = l0 * __expf(m0 - m0n) + wsum(p0);
            l1 = l1 * __expf(m1 - m1n) + wsum(p1);
            m0 = m0n; m1 = m1n;
        }
        float r0 = __builtin_amdgcn_rcpf(l0);
        float r1 = __builtin_amdgcn_rcpf(l1);
        for (int base = row; base < end; base += 64) {
            int idx = base + lane;
            bool act = idx < end;
            int sidx = idx - row;
            int src; float e0, e1;
            if (sidx < STASH_CAP) {
                float4 se = stashE[wid][sidx];
                src = __float_as_int(se.x);
                e0 = se.y; e1 = se.z;
            } else {
                src = act ? csr[idx] : 0;
                float2 av = asp[src];
                e0 = av.x + adv.x; e1 = av.y + adv.y;
                e0 = e0 > 0.f ? e0 : NEG_SLOPE * e0;
                e1 = e1 > 0.f ? e1 : NEG_SLOPE * e1;
            }
            if (!act) src = 0;  // mask garbage LDS src (address safety)
            float a0 = act ? __expf(e0 - m0) * r0 : 0.f;
            float a1 = act ? __expf(e1 - m1) * r1 : 0.f;
            stashA[wid][lane] = make_float2(__int_as_float(src), a0);
            stashA[wid][64 + lane] = make_float2(__int_as_float(src), a1);
            int cnt = min(64, end - base);
            for (int j = 0; j < cnt; j += 4) {
                float2 sa = stashA[wid][head_off + j + eg];
                int sj = __float_as_int(sa.x);
                float aj = sa.y;
                uint4 u = *(const uint4*)(h1base + (((unsigned)sj) << 8) + flbase);
                acc[0] += bflo(u.x) * aj; acc[1] += bfhi(u.x) * aj;
                acc[2] += bflo(u.y) * aj; acc[3] += bfhi(u.y) * aj;
                acc[4] += bflo(u.z) * aj; acc[5] += bfhi(u.z) * aj;
                acc[6] += bflo(u.w) * aj; acc[7] += bfhi(u.w) * aj;
            }
        }
    }
    // merge the 4 edge subgroups (eg = lane bits 4,5)
#pragma unroll
    for (int i = 0; i < 8; ++i) {
        acc[i] += __shfl_xor(acc[i], 16);
        acc[i] += __shfl_xor(acc[i], 32);
    }
    if (lane < 16) {
        float inv = (lane >= 8) ? inv1 : inv0;
        float4 ba = ((const float4*)b1)[lane * 2];
        float4 bb4 = ((const float4*)b1)[lane * 2 + 1];
        float v[8];
        v[0] = acc[0] * inv + ba.x;  v[1] = acc[1] * inv + ba.y;
        v[2] = acc[2] * inv + ba.z;  v[3] = acc[3] * inv + ba.w;
        v[4] = acc[4] * inv + bb4.x; v[5] = acc[5] * inv + bb4.y;
        v[6] = acc[6] * inv + bb4.z; v[7] = acc[7] * inv + bb4.w;
#pragma unroll
        for (int i = 0; i < 8; ++i) v[i] = v[i] > 0.f ? v[i] : __expf(v[i]) - 1.f;
        uint4 pk;
        pk.x = bfpack(v[0], v[1]); pk.y = bfpack(v[2], v[3]);
        pk.z = bfpack(v[4], v[5]); pk.w = bfpack(v[6], v[7]);
        ((uint4*)aggb)[(size_t)n * 16 + lane] = pk;
    }
}

// h2 = agg1 @ W2 (agg bf16 in, h2 bf16 out) + att2 dots. 64 nodes/block.
// h2b rows padded to 32 ushorts (64B, cache-line aligned).
__global__ __launch_bounds__(256, 4) void k_node2(const unsigned* __restrict__ aggb,
                                                  const float* __restrict__ W2,
                                                  const float* __restrict__ as_g,
                                                  const float* __restrict__ ad_g,
                                                  ushort_t* __restrict__ h2b,
                                                  float* __restrict__ a_s,
                                                  float* __restrict__ a_d, int N) {
    __shared__ float al[64 * 132];   // [node][k] padded
    __shared__ float w2t[20 * 132];  // [c][k] padded, cols 18,19 zero
    int t = threadIdx.x;
    int n0 = blockIdx.x * 64;
#pragma unroll
    for (int i = 0; i < 4; ++i) {
        int f = t + i * 256;            // 0..1023
        int node = f >> 4, q = f & 15;  // row = 64 uints = 16 uint4
        int ng = n0 + node; if (ng > N - 1) ng = N - 1;
        uint4 u = ((const uint4*)aggb)[(size_t)ng * 16 + q];
        float* dst = &al[node * 132 + q * 8];
        dst[0] = bflo(u.x); dst[1] = bfhi(u.x);
        dst[2] = bflo(u.y); dst[3] = bfhi(u.y);
        dst[4] = bflo(u.z); dst[5] = bfhi(u.z);
        dst[6] = bflo(u.w); dst[7] = bfhi(u.w);
    }
    for (int i = t; i < 2560; i += 256) {
        int c = i >> 7, k = i & 127;
        w2t[c * 132 + k] = (c < 18) ? W2[k * 18 + c] : 0.f;
    }
    __syncthreads();
    int node = t >> 2;
    int cq = t & 3;
    int c0 = cq * 5;  // cols c0..c0+4 (cq==3: cols 15..19, 18/19 dead)
    int n = n0 + node;
    float acc[5] = {0.f, 0.f, 0.f, 0.f, 0.f};
#pragma unroll 2
    for (int k4 = 0; k4 < 128; k4 += 4) {
        float4 a = *(float4*)&al[node * 132 + k4];
#pragma unroll
        for (int i = 0; i < 5; ++i) {
            float4 w = *(float4*)&w2t[(c0 + i) * 132 + k4];
            acc[i] += a.x * w.x + a.y * w.y + a.z * w.z + a.w * w.w;
        }
    }
    float ps = 0.f, pd = 0.f;
#pragma unroll
    for (int i = 0; i < 5; ++i) {
        int c = c0 + i;
        float asv = (c < 18) ? as_g[c] : 0.f;
        float adv = (c < 18) ? ad_g[c] : 0.f;
        ps += acc[i] * asv;
        pd += acc[i] * adv;
    }
    ps += __shfl_xor(ps, 1); ps += __shfl_xor(ps, 2);
    pd += __shfl_xor(pd, 1); pd += __shfl_xor(pd, 2);
    if (n < N) {
#pragma unroll
        for (int i = 0; i < 5; ++i) {
            int c = c0 + i;
            if (c < 18) h2b[(size_t)n * 32 + c] = bf16of(acc[i]);
        }
        if (cq == 0) { a_s[n] = ps; a_d[n] = pd; }
    }
}

// ---- layer-2 fused, v6: h2b rows 64B-aligned (stride 32) ----
__global__ __launch_bounds__(256) void k_node_l2(const int* __restrict__ rs,
                                                 const int* __restrict__ csr,
                                                 const ushort_t* __restrict__ h2b,
                                                 const float* __restrict__ as2,
                                                 const float* __restrict__ ad2,
                                                 const float* __restrict__ b2,
                                                 float* __restrict__ out, int N) {
    __shared__ float2 stash[4][STASH_CAP];  // fast: (src,p); slow: (src,e)
    int wid = threadIdx.x >> 6;
    int lane = threadIdx.x & 63;
    int n = (blockIdx.x * 256 + threadIdx.x) >> 6;
    if (n >= N) return;
    int row = rs[n], end = rs[n + 1];
    int deg = end - row;
    float adn = ad2[n];
    int g = lane / 21;            // 0..3 (lane 63 -> g=3, acc discarded)
    int c = lane - g * 21;        // 0..20
    int cc = c < 18 ? c : 17;     // clamp for safe loads
    float acc = 0.f;
    float post;
    if (deg <= 64) {
        // ---- fast: single pass, unnormalized p; scale after group-sum ----
        bool act = lane < deg;
        int src = act ? csr[row + lane] : 0;
        float e = as2[src] + adn;
        e = e > 0.f ? e : NEG_SLOPE * e;
        if (!act) e = -INFINITY;
        float m = wmax(e);
        float p = act ? __expf(e - m) : 0.f;
        post = __builtin_amdgcn_rcpf(wsum(p));
        stash[wid][lane] = make_float2(__int_as_float(src), p);
        // 2-deep pipeline over this group's edges
        int o = g;
        for (; o + 3 < deg; o += 6) {
            float2 s0 = stash[wid][o];
            float2 s1 = stash[wid][o + 3];
            int q0 = __float_as_int(s0.x);
            int q1 = __float_as_int(s1.x);
            float v0 = bfval(h2b[(size_t)q0 * 32 + cc]);
            float v1 = bfval(h2b[(size_t)q1 * 32 + cc]);
            acc += s0.y * v0 + s1.y * v1;
        }
        if (o < deg) {
            float2 s0 = stash[wid][o];
            int q0 = __float_as_int(s0.x);
            acc += s0.y * bfval(h2b[(size_t)q0 * 32 + cc]);
        }
    } else {
        // ---- slow path (deg>64; not taken on this input) ----
        post = 1.f;
        float m = -INFINITY, l = 0.f;
        for (int base = row; base < end; base += 64) {
            int idx = base + lane;
            bool act = idx < end;
            int src = act ? csr[idx] : 0;
            float e = as2[src] + adn;
            e = e > 0.f ? e : NEG_SLOPE * e;
            int sidx = idx - row;
            if (act && sidx < STASH_CAP)
                stash[wid][sidx] = make_float2(__int_as_float(src), e);
            if (!act) e = -INFINITY;
            float mn = fmaxf(m, wmax(e));
            float p = act ? __expf(e - mn) : 0.f;
            l = l * __expf(m - mn) + wsum(p);
            m = mn;
        }
        float invl = __builtin_amdgcn_rcpf(l);
        int lim = deg < STASH_CAP ? deg : STASH_CAP;
        for (int o = g; o < lim; o += 3) {
            float2 se = stash[wid][o];
            int src = __float_as_int(se.x);
            float alpha = __expf(se.y - m) * invl;
            acc += alpha * bfval(h2b[(size_t)src * 32 + cc]);
        }
        for (int pos = row + STASH_CAP + g; pos < end; pos += 3) {
            int src = csr[pos];
            float e = as2[src] + adn;
            e = e > 0.f ? e : NEG_SLOPE * e;
            float alpha = __expf(e - m) * invl;
            acc += alpha * bfval(h2b[(size_t)src * 32 + cc]);
        }
    }
    // group-sum into lanes 0..17: both shfls read pre-mutation acc
    float t1 = __shfl(acc, (lane + 21) & 63);
    float t2 = __shfl(acc, (lane + 42) & 63);
    acc += t1 + t2;
    float bb = (lane < 18) ? b2[lane] : 0.f;
    float v = acc * post + bb;
    // ---- lane-parallel log-softmax over lanes 0..17 (32-lane xor net) ----
    float tmx = (lane < 18) ? v : -INFINITY;
    for (int o = 16; o; o >>= 1) tmx = fmaxf(tmx, __shfl_xor(tmx, o));
    float s = (lane < 18) ? __expf(v - tmx) : 0.f;
    for (int o = 16; o; o >>= 1) s += __shfl_xor(s, o);
    float lse = tmx + __logf(s);
    if (lane < 18) out[(size_t)n * 18 + lane] = v - lse;
}

extern "C" void kernel_launch(void* const* d_in, const int* in_sizes, int n_in,
                              void* d_out, int out_size, void* d_ws, size_t ws_size,
                              hipStream_t stream) {
    const float* x      = (const float*)d_in[0];
    const int*   ei     = (const int*)d_in[1];
    const float* W0     = (const float*)d_in[2];
    const float* b0     = (const float*)d_in[3];
    const float* W1     = (const float*)d_in[4];
    const float* att_s1 = (const float*)d_in[5];
    const float* att_d1 = (const float*)d_in[6];
    const float* b1     = (const float*)d_in[7];
    const float* W2     = (const float*)d_in[8];
    const float* att_s2 = (const float*)d_in[9];
    const float* att_d2 = (const float*)d_in[10];
    const float* b2     = (const float*)d_in[11];

    const int N = in_sizes[0] / 128;
    const int E = in_sizes[1] / 2;
    const int Etot = E + N;
    const int NB = (N + 1023) / 1024;  // scan blocks (<= 256)
    const int NBLK = (N + 63) / 64;    // dense tiles

    // workspace carve-up (~82 MB)
    char* w = (char*)d_ws;
    ushort_t* h1b  = (ushort_t*)w; w += (size_t)N * 128 * 2;
    unsigned* aggb = (unsigned*)w; w += (size_t)N * 128 * 2;  // bf16 x 128
    float* as1     = (float*)w;    w += (size_t)N * 2 * 4;
    float* ad1     = (float*)w;    w += (size_t)N * 2 * 4;
    ushort_t* h2b  = (ushort_t*)w; w += (size_t)N * 32 * 2;   // 64B-aligned rows
    float* as2     = (float*)w;    w += (size_t)N * 4;
    float* ad2     = (float*)w;    w += (size_t)N * 4;
    int* deg       = (int*)w;      w += (size_t)N * 4;
    int* rs        = (int*)w;      w += (size_t)(N + 1) * 4;
    int* bsum      = (int*)w;      w += (size_t)256 * 4;
    int* boff      = (int*)w;      w += (size_t)256 * 4;
    int* eofs      = (int*)w;      w += (size_t)E * 4;
    int* csr       = (int*)w;      w += (size_t)Etot * 4;

    float* out = (float*)d_out;

    // ---- cooperative CSR build (one launch) ----
    {
        int n_ = N, e_ = E, et_ = Etot, nb_ = NB;
        void* args[] = {(void*)&ei, (void*)&deg, (void*)&eofs, (void*)&rs,
                        (void*)&bsum, (void*)&boff, (void*)&csr,
                        (void*)&n_, (void*)&e_, (void*)&et_, (void*)&nb_};
        hipLaunchCooperativeKernel((void*)k_csr, dim3(1024), dim3(256), args, 0, stream);
    }

    // ---- fused dense front-end (256 threads) ----
    k_gemm12<<<NBLK, 256, 0, stream>>>(x, W0, b0, W1, att_s1, att_d1, h1b, as1, ad1, N);

    // ---- layer 1 fused edge pass ----
    k_node_l1<<<(N * 64 + 255) / 256, 256, 0, stream>>>(rs, csr, h1b, as1, ad1, b1, aggb, N);

    // ---- layer 2 dense + fused edge pass ----
    k_node2<<<NBLK, 256, 0, stream>>>(aggb, W2, att_s2, att_d2, h2b, as2, ad2, N);
    k_node_l2<<<(N * 64 + 255) / 256, 256, 0, stream>>>(rs, csr, h2b, as2, ad2, b2, out, N);
}

// Round 11
// 431.527 us; speedup vs baseline: 2.1279x; 2.1279x over previous
//
#include <hip/hip_runtime.h>
#include <math.h>

// GAT 2-layer: N=100000, E=1600000 (+N self loops), F_IN=128, HID=64, HEADS=2,
// OUT_HEADS=1, NUM_CLASS=18, NEG_SLOPE=0.2
// Round 19 (resubmit; R10 was a container-acquisition failure, kernel never
// ran): REVERT to best-known composition after two falsified experiments
// (R18 coop CSR: 590us, grid-wide barriers + grid-stride = 283GB/s disaster;
// R17 gemm12@512: occupancy stuck 17%, 93.9us). This file = R15 CSR chain
// (separate kernels, eofs form) + gemm12@256 fused (76.5us measured) + R13
// k_node_l1 (76.1us, fabric-bound floor) + node2/l2 with stride-32 h2b.
// Measured evidence bank: l1 FETCH 213MB @ 3.2TB/s fabric; deg_edges atomics
// generate ~70MB coherence write traffic (R18 WRITE_SIZE); gemm12 is
// latency-bound at 2 blocks/CU (66.5KB LDS).

#define NEG_SLOPE 0.2f
#define STASH_CAP 128

typedef unsigned short ushort_t;

// ---------------- wave reductions (64 lanes) ----------------
__device__ __forceinline__ float wmax(float v) {
    for (int o = 32; o; o >>= 1) v = fmaxf(v, __shfl_xor(v, o));
    return v;
}
__device__ __forceinline__ float wsum(float v) {
    for (int o = 32; o; o >>= 1) v += __shfl_xor(v, o);
    return v;
}

// ---------------- bf16 helpers (RNE) ----------------
__device__ __forceinline__ unsigned bfpack(float a, float b) {
    unsigned ua = __float_as_uint(a);
    unsigned ub = __float_as_uint(b);
    ua = (ua + 0x7fffu + ((ua >> 16) & 1u)) >> 16;
    ub = (ub + 0x7fffu + ((ub >> 16) & 1u)) & 0xffff0000u;
    return ua | ub;
}
__device__ __forceinline__ ushort_t bf16of(float a) {
    unsigned ua = __float_as_uint(a);
    return (ushort_t)((ua + 0x7fffu + ((ua >> 16) & 1u)) >> 16);
}
__device__ __forceinline__ float bflo(unsigned u) { return __uint_as_float(u << 16); }
__device__ __forceinline__ float bfhi(unsigned u) { return __uint_as_float(u & 0xffff0000u); }
__device__ __forceinline__ float bfval(ushort_t u) { return __uint_as_float(((unsigned)u) << 16); }

// ---------------- CSR build (R15 form) ----------------
__global__ void k_deg_init(int* __restrict__ deg, int N) {
    int i = blockIdx.x * blockDim.x + threadIdx.x;
    if (i < N) deg[i] = 1;  // slot 0 reserved for self loop
}
__global__ void k_deg_edges(const int* __restrict__ ei, int* __restrict__ deg,
                            int* __restrict__ eofs, int E) {
    int e = blockIdx.x * blockDim.x + threadIdx.x;
    if (e < E) eofs[e] = atomicAdd(&deg[ei[E + e]], 1);
}

__global__ __launch_bounds__(256) void k_scan1(const int* __restrict__ deg, int* __restrict__ rs,
                                               int* __restrict__ bsum, int N) {
    __shared__ int s[256];
    int t = threadIdx.x;
    int base = blockIdx.x * 1024;
    int i0 = base + t * 4;
    int d0 = (i0 + 0 < N) ? deg[i0 + 0] : 0;
    int d1 = (i0 + 1 < N) ? deg[i0 + 1] : 0;
    int d2 = (i0 + 2 < N) ? deg[i0 + 2] : 0;
    int d3 = (i0 + 3 < N) ? deg[i0 + 3] : 0;
    int s0 = d0, s1 = s0 + d1, s2 = s1 + d2, s3 = s2 + d3;
    int tsum = s3;
    s[t] = tsum;
    __syncthreads();
    for (int off = 1; off < 256; off <<= 1) {
        int v = (t >= off) ? s[t - off] : 0;
        __syncthreads();
        s[t] += v;
        __syncthreads();
    }
    int excl = s[t] - tsum;
    if (i0 + 0 < N) rs[1 + i0 + 0] = excl + s0;
    if (i0 + 1 < N) rs[1 + i0 + 1] = excl + s1;
    if (i0 + 2 < N) rs[1 + i0 + 2] = excl + s2;
    if (i0 + 3 < N) rs[1 + i0 + 3] = excl + s3;
    if (t == 0) bsum[blockIdx.x] = s[255];
}

__global__ __launch_bounds__(256) void k_scan2(const int* __restrict__ bsum,
                                               int* __restrict__ boff, int NB) {
    __shared__ int s[256];
    int t = threadIdx.x;
    int orig = (t < NB) ? bsum[t] : 0;
    s[t] = orig;
    __syncthreads();
    for (int off = 1; off < 256; off <<= 1) {
        int v = (t >= off) ? s[t - off] : 0;
        __syncthreads();
        s[t] += v;
        __syncthreads();
    }
    if (t < NB) boff[t] = s[t] - orig;  // exclusive
}

__global__ void k_scan3(int* __restrict__ rs, const int* __restrict__ boff, int N) {
    int i = blockIdx.x * blockDim.x + threadIdx.x;
    if (i == 0) rs[0] = 0;
    if (i < N) rs[1 + i] += boff[i >> 10];
}

// slice-filtered, atomic-free scatter (csr lines stay in one XCD L2).
__global__ __launch_bounds__(256) void k_scatter(const int* __restrict__ ei,
                                                 const int* __restrict__ eofs,
                                                 const int* __restrict__ rs,
                                                 int* __restrict__ csr,
                                                 int E, int Etot, int cohortBlocks) {
    int c = blockIdx.x & 7;
    int pb = blockIdx.x >> 3;
    int tid = pb * 256 + threadIdx.x;
    int stride = cohortBlocks * 256;
    for (int e = tid; e < Etot; e += stride) {
        int dst = (e < E) ? ei[E + e] : (e - E);
        if (((dst >> 13) & 7) != c) continue;
        int src, ofs;
        if (e < E) { src = ei[e]; ofs = eofs[e]; } else { src = dst; ofs = 0; }
        csr[rs[dst] + ofs] = src;
    }
}

// ---------------- fused dense front-end, 256 threads (R16 form, 76.5us) ----------------
// phase A: h0 = relu(x @ W0 + b0) kept in LDS (fp32).
// phase B: h1 = h0 @ W1 (bf16 out) + fused att1 dots.
// LDS: [0,8448): al (x tile [64][132]) then al2 (h0 [64][68]);
//      [8448,16640): W0 [128][64] then W1 [64][128]. 66.5KB -> 2 blocks/CU.
__global__ __launch_bounds__(256) void k_gemm12(const float* __restrict__ x,
                                                const float* __restrict__ W0,
                                                const float* __restrict__ b0,
                                                const float* __restrict__ W1,
                                                const float* __restrict__ as_g,
                                                const float* __restrict__ ad_g,
                                                ushort_t* __restrict__ h1b,
                                                float* __restrict__ as1,
                                                float* __restrict__ ad1, int N) {
    __shared__ float smem[16640];
    float* al  = smem;          // phase A x tile
    float* wl  = smem + 8448;   // phase A W0; phase B W1
    float* al2 = smem;          // phase B h0 tile [64][68]
    int t = threadIdx.x;
    int n0 = blockIdx.x * 64;
    // ---- phase A loads ----
    {
        const float4* wg = (const float4*)W0;
        float4* wl4 = (float4*)wl;
#pragma unroll
        for (int i = 0; i < 8; ++i) wl4[t + i * 256] = wg[t + i * 256];
#pragma unroll
        for (int i = 0; i < 8; ++i) {
            int f = t + i * 256;
            int node = f >> 5, q = f & 31;
            int ng = n0 + node; if (ng > N - 1) ng = N - 1;
            float4 v = ((const float4*)x)[(size_t)ng * 32 + q];
            *(float4*)&al[node * 132 + q * 4] = v;
        }
    }
    __syncthreads();
    // ---- phase A compute ----
    int colg = t & 15;   // cols colg*4..+3
    int rowg = t >> 4;   // rows rowg*4..+3
    float4 acc[4];
#pragma unroll
    for (int j = 0; j < 4; ++j) acc[j] = make_float4(0.f, 0.f, 0.f, 0.f);
    for (int k4 = 0; k4 < 128; k4 += 4) {
        float4 w0 = *(float4*)&wl[(k4 + 0) * 64 + colg * 4];
        float4 w1 = *(float4*)&wl[(k4 + 1) * 64 + colg * 4];
        float4 w2 = *(float4*)&wl[(k4 + 2) * 64 + colg * 4];
        float4 w3 = *(float4*)&wl[(k4 + 3) * 64 + colg * 4];
#pragma unroll
        for (int j = 0; j < 4; ++j) {
            float4 a = *(float4*)&al[(rowg * 4 + j) * 132 + k4];
            acc[j].x += a.x * w0.x + a.y * w1.x + a.z * w2.x + a.w * w3.x;
            acc[j].y += a.x * w0.y + a.y * w1.y + a.z * w2.y + a.w * w3.y;
            acc[j].z += a.x * w0.z + a.y * w1.z + a.z * w2.z + a.w * w3.z;
            acc[j].w += a.x * w0.w + a.y * w1.w + a.z * w2.w + a.w * w3.w;
        }
    }
    float4 bb = ((const float4*)b0)[colg];
    float4 h0v[4];
#pragma unroll
    for (int j = 0; j < 4; ++j) {
        h0v[j].x = fmaxf(acc[j].x + bb.x, 0.f);
        h0v[j].y = fmaxf(acc[j].y + bb.y, 0.f);
        h0v[j].z = fmaxf(acc[j].z + bb.z, 0.f);
        h0v[j].w = fmaxf(acc[j].w + bb.w, 0.f);
    }
    __syncthreads();  // all al/wl reads of phase A complete
    // ---- stage h0 to LDS, load W1 ----
#pragma unroll
    for (int j = 0; j < 4; ++j)
        *(float4*)&al2[(rowg * 4 + j) * 68 + colg * 4] = h0v[j];
    {
        const float4* wg1 = (const float4*)W1;
        float4* wl4 = (float4*)wl;
#pragma unroll
        for (int i = 0; i < 8; ++i) wl4[t + i * 256] = wg1[t + i * 256];
    }
    __syncthreads();
    // ---- phase B compute ----
    int colg2 = t & 31;  // cols colg2*4..+3 (head = colg2>=16)
    int rowg2 = t >> 5;  // rows rowg2*8..+7
    float4 acc2[8];
#pragma unroll
    for (int j = 0; j < 8; ++j) acc2[j] = make_float4(0.f, 0.f, 0.f, 0.f);
    for (int k4 = 0; k4 < 64; k4 += 4) {
        float4 w0 = *(float4*)&wl[(k4 + 0) * 128 + colg2 * 4];
        float4 w1 = *(float4*)&wl[(k4 + 1) * 128 + colg2 * 4];
        float4 w2 = *(float4*)&wl[(k4 + 2) * 128 + colg2 * 4];
        float4 w3 = *(float4*)&wl[(k4 + 3) * 128 + colg2 * 4];
#pragma unroll
        for (int j = 0; j < 8; ++j) {
            float4 a = *(float4*)&al2[(rowg2 * 8 + j) * 68 + k4];
            acc2[j].x += a.x * w0.x + a.y * w1.x + a.z * w2.x + a.w * w3.x;
            acc2[j].y += a.x * w0.y + a.y * w1.y + a.z * w2.y + a.w * w3.y;
            acc2[j].z += a.x * w0.z + a.y * w1.z + a.z * w2.z + a.w * w3.z;
            acc2[j].w += a.x * w0.w + a.y * w1.w + a.z * w2.w + a.w * w3.w;
        }
    }
    float4 asv = ((const float4*)as_g)[colg2];
    float4 adv = ((const float4*)ad_g)[colg2];
    float ps[8], pd[8];
#pragma unroll
    for (int j = 0; j < 8; ++j) {
        ps[j] = acc2[j].x * asv.x + acc2[j].y * asv.y + acc2[j].z * asv.z + acc2[j].w * asv.w;
        pd[j] = acc2[j].x * adv.x + acc2[j].y * adv.y + acc2[j].z * adv.z + acc2[j].w * adv.w;
    }
    for (int o = 1; o < 16; o <<= 1) {
#pragma unroll
        for (int j = 0; j < 8; ++j) {
            ps[j] += __shfl_xor(ps[j], o);
            pd[j] += __shfl_xor(pd[j], o);
        }
    }
#pragma unroll
    for (int j = 0; j < 8; ++j) {
        int n = n0 + rowg2 * 8 + j;
        if (n < N) {
            uint2 pr;
            pr.x = bfpack(acc2[j].x, acc2[j].y);
            pr.y = bfpack(acc2[j].z, acc2[j].w);
            ((uint2*)h1b)[(size_t)n * 32 + colg2] = pr;  // 32 uint2 per row
        }
    }
    int lane = t & 63;
    if ((lane & 15) == 0) {
        int head = (lane >> 4) & 1;
#pragma unroll
        for (int j = 0; j < 8; ++j) {
            int n = n0 + rowg2 * 8 + j;
            if (n < N) {
                as1[n * 2 + head] = ps[j];
                ad1[n * 2 + head] = pd[j];
            }
        }
    }
}

// ---- layer-1 fused, v7 (R13): single-pass softmax (deg<=64), rotated pipeline ----
__global__ __launch_bounds__(256) void k_node_l1(const int* __restrict__ rs,
                                                 const int* __restrict__ csr,
                                                 const ushort_t* __restrict__ h1b,
                                                 const float* __restrict__ as1,
                                                 const float* __restrict__ ad1,
                                                 const float* __restrict__ b1,
                                                 unsigned* __restrict__ aggb, int N) {
    __shared__ float2 stashA[4][128];        // [wid][head*64+edge]
    __shared__ float4 stashE[4][STASH_CAP];  // slow path only
    int wid = threadIdx.x >> 6;
    int lane = threadIdx.x & 63;
    int n = (blockIdx.x * 256 + threadIdx.x) >> 6;
    if (n >= N) return;
    int row = rs[n], end = rs[n + 1];
    int deg = end - row;
    float2 adv = ((const float2*)ad1)[n];
    const float2* asp = (const float2*)as1;
    const char* h1base = (const char*)h1b;
    int eg = lane >> 4;                 // 0..3
    int fl = lane & 15;                 // 0..15
    int head_off = (fl >= 8) ? 64 : 0;
    int flbase = fl * 16;               // byte offset within 256B row
    float acc[8] = {0.f, 0.f, 0.f, 0.f, 0.f, 0.f, 0.f, 0.f};
    float inv0, inv1;
    if (deg <= 64) {
        // ---- fast path: single pass ----
        bool act = lane < deg;
        int src = act ? csr[row + lane] : 0;
        float2 av = asp[src];
        float e0 = av.x + adv.x, e1 = av.y + adv.y;
        e0 = e0 > 0.f ? e0 : NEG_SLOPE * e0;
        e1 = e1 > 0.f ? e1 : NEG_SLOPE * e1;
        if (!act) { e0 = -INFINITY; e1 = -INFINITY; }
        float m0 = wmax(e0), m1 = wmax(e1);
        float p0 = act ? __expf(e0 - m0) : 0.f;
        float p1 = act ? __expf(e1 - m1) : 0.f;
        inv0 = __builtin_amdgcn_rcpf(wsum(p0));
        inv1 = __builtin_amdgcn_rcpf(wsum(p1));
        stashA[wid][lane] = make_float2(__int_as_float(src), p0);
        stashA[wid][64 + lane] = make_float2(__int_as_float(src), p1);
        // rotated software pipeline at 8-edge granularity: prefetch j+8's
        // stash pair + gathers before FMAs of j. Pad entries: p=0/src=0.
        int deg8 = (deg + 7) & ~7;
        int b0i = head_off + eg;
        float2 sa0 = stashA[wid][b0i];
        float2 sa1 = stashA[wid][b0i + 4];
        uint4 u0 = *(const uint4*)(h1base + (((unsigned)__float_as_int(sa0.x)) << 8) + flbase);
        uint4 u1 = *(const uint4*)(h1base + (((unsigned)__float_as_int(sa1.x)) << 8) + flbase);
        for (int j = 0; j < deg8; j += 8) {
            int jn = (j + 8 < deg8) ? j + 8 : 0;  // wrap: hot reload, unused
            float2 sb0 = stashA[wid][b0i + jn];
            float2 sb1 = stashA[wid][b0i + jn + 4];
            uint4 v0 = *(const uint4*)(h1base + (((unsigned)__float_as_int(sb0.x)) << 8) + flbase);
            uint4 v1 = *(const uint4*)(h1base + (((unsigned)__float_as_int(sb1.x)) << 8) + flbase);
            float a0 = sa0.y, a1 = sa1.y;
            acc[0] += bflo(u0.x) * a0; acc[1] += bfhi(u0.x) * a0;
            acc[2] += bflo(u0.y) * a0; acc[3] += bfhi(u0.y) * a0;
            acc[4] += bflo(u0.z) * a0; acc[5] += bfhi(u0.z) * a0;
            acc[6] += bflo(u0.w) * a0; acc[7] += bfhi(u0.w) * a0;
            acc[0] += bflo(u1.x) * a1; acc[1] += bfhi(u1.x) * a1;
            acc[2] += bflo(u1.y) * a1; acc[3] += bfhi(u1.y) * a1;
            acc[4] += bflo(u1.z) * a1; acc[5] += bfhi(u1.z) * a1;
            acc[6] += bflo(u1.w) * a1; acc[7] += bfhi(u1.w) * a1;
            sa0 = sb0; sa1 = sb1; u0 = v0; u1 = v1;
        }
    } else {
        // ---- slow path (deg>64; not taken on this input): two-pass ----
        inv0 = 1.f; inv1 = 1.f;  // stash holds normalized alpha
        float m0 = -INFINITY, m1 = -INFINITY, l0 = 0.f, l1 = 0.f;
        for (int base = row; base < end; base += 64) {
            int idx = base + lane;
            bool act = idx < end;
            int src = act ? csr[idx] : 0;
            float2 av = asp[src];
            float e0 = av.x + adv.x, e1 = av.y + adv.y;
            e0 = e0 > 0.f ? e0 : NEG_SLOPE * e0;
            e1 = e1 > 0.f ? e1 : NEG_SLOPE * e1;
            int sidx = idx - row;
            if (act && sidx < STASH_CAP)
                stashE[wid][sidx] = make_float4(__int_as_float(src), e0, e1, 0.f);
            if (!act) { e0 = -INFINITY; e1 = -INFINITY; }
            float m0n = fmaxf(m0, wmax(e0));
            float m1n = fmaxf(m1, wmax(e1));
            float p0 = act ? __expf(e0 - m0n) : 0.f;
            float p1 = act ? __expf(e1 - m1n) : 0.f;
            l0 = l0 * __expf(m0 - m0n) + wsum(p0);
            l1 = l1 * __expf(m1 - m1n) + wsum(p1);
            m0 = m0n; m1 = m1n;
        }
        float r0 = __builtin_amdgcn_rcpf(l0);
        float r1 = __builtin_amdgcn_rcpf(l1);
        for (int base = row; base < end; base += 64) {
            int idx = base + lane;
            bool act = idx < end;
            int sidx = idx - row;
            int src; float e0, e1;
            if (sidx < STASH_CAP) {
                float4 se = stashE[wid][sidx];
                src = __float_as_int(se.x);
                e0 = se.y; e1 = se.z;
            } else {
                src = act ? csr[idx] : 0;
                float2 av = asp[src];
                e0 = av.x + adv.x; e1 = av.y + adv.y;
                e0 = e0 > 0.f ? e0 : NEG_SLOPE * e0;
                e1 = e1 > 0.f ? e1 : NEG_SLOPE * e1;
            }
            if (!act) src = 0;  // mask garbage LDS src (address safety)
            float a0 = act ? __expf(e0 - m0) * r0 : 0.f;
            float a1 = act ? __expf(e1 - m1) * r1 : 0.f;
            stashA[wid][lane] = make_float2(__int_as_float(src), a0);
            stashA[wid][64 + lane] = make_float2(__int_as_float(src), a1);
            int cnt = min(64, end - base);
            for (int j = 0; j < cnt; j += 4) {
                float2 sa = stashA[wid][head_off + j + eg];
                int sj = __float_as_int(sa.x);
                float aj = sa.y;
                uint4 u = *(const uint4*)(h1base + (((unsigned)sj) << 8) + flbase);
                acc[0] += bflo(u.x) * aj; acc[1] += bfhi(u.x) * aj;
                acc[2] += bflo(u.y) * aj; acc[3] += bfhi(u.y) * aj;
                acc[4] += bflo(u.z) * aj; acc[5] += bfhi(u.z) * aj;
                acc[6] += bflo(u.w) * aj; acc[7] += bfhi(u.w) * aj;
            }
        }
    }
    // merge the 4 edge subgroups (eg = lane bits 4,5)
#pragma unroll
    for (int i = 0; i < 8; ++i) {
        acc[i] += __shfl_xor(acc[i], 16);
        acc[i] += __shfl_xor(acc[i], 32);
    }
    if (lane < 16) {
        float inv = (lane >= 8) ? inv1 : inv0;
        float4 ba = ((const float4*)b1)[lane * 2];
        float4 bb4 = ((const float4*)b1)[lane * 2 + 1];
        float v[8];
        v[0] = acc[0] * inv + ba.x;  v[1] = acc[1] * inv + ba.y;
        v[2] = acc[2] * inv + ba.z;  v[3] = acc[3] * inv + ba.w;
        v[4] = acc[4] * inv + bb4.x; v[5] = acc[5] * inv + bb4.y;
        v[6] = acc[6] * inv + bb4.z; v[7] = acc[7] * inv + bb4.w;
#pragma unroll
        for (int i = 0; i < 8; ++i) v[i] = v[i] > 0.f ? v[i] : __expf(v[i]) - 1.f;
        uint4 pk;
        pk.x = bfpack(v[0], v[1]); pk.y = bfpack(v[2], v[3]);
        pk.z = bfpack(v[4], v[5]); pk.w = bfpack(v[6], v[7]);
        ((uint4*)aggb)[(size_t)n * 16 + lane] = pk;
    }
}

// h2 = agg1 @ W2 (agg bf16 in, h2 bf16 out) + att2 dots. 64 nodes/block.
// h2b rows padded to 32 ushorts (64B, cache-line aligned).
__global__ __launch_bounds__(256, 4) void k_node2(const unsigned* __restrict__ aggb,
                                                  const float* __restrict__ W2,
                                                  const float* __restrict__ as_g,
                                                  const float* __restrict__ ad_g,
                                                  ushort_t* __restrict__ h2b,
                                                  float* __restrict__ a_s,
                                                  float* __restrict__ a_d, int N) {
    __shared__ float al[64 * 132];   // [node][k] padded
    __shared__ float w2t[20 * 132];  // [c][k] padded, cols 18,19 zero
    int t = threadIdx.x;
    int n0 = blockIdx.x * 64;
#pragma unroll
    for (int i = 0; i < 4; ++i) {
        int f = t + i * 256;            // 0..1023
        int node = f >> 4, q = f & 15;  // row = 64 uints = 16 uint4
        int ng = n0 + node; if (ng > N - 1) ng = N - 1;
        uint4 u = ((const uint4*)aggb)[(size_t)ng * 16 + q];
        float* dst = &al[node * 132 + q * 8];
        dst[0] = bflo(u.x); dst[1] = bfhi(u.x);
        dst[2] = bflo(u.y); dst[3] = bfhi(u.y);
        dst[4] = bflo(u.z); dst[5] = bfhi(u.z);
        dst[6] = bflo(u.w); dst[7] = bfhi(u.w);
    }
    for (int i = t; i < 2560; i += 256) {
        int c = i >> 7, k = i & 127;
        w2t[c * 132 + k] = (c < 18) ? W2[k * 18 + c] : 0.f;
    }
    __syncthreads();
    int node = t >> 2;
    int cq = t & 3;
    int c0 = cq * 5;  // cols c0..c0+4 (cq==3: cols 15..19, 18/19 dead)
    int n = n0 + node;
    float acc[5] = {0.f, 0.f, 0.f, 0.f, 0.f};
#pragma unroll 2
    for (int k4 = 0; k4 < 128; k4 += 4) {
        float4 a = *(float4*)&al[node * 132 + k4];
#pragma unroll
        for (int i = 0; i < 5; ++i) {
            float4 w = *(float4*)&w2t[(c0 + i) * 132 + k4];
            acc[i] += a.x * w.x + a.y * w.y + a.z * w.z + a.w * w.w;
        }
    }
    float ps = 0.f, pd = 0.f;
#pragma unroll
    for (int i = 0; i < 5; ++i) {
        int c = c0 + i;
        float asv = (c < 18) ? as_g[c] : 0.f;
        float adv = (c < 18) ? ad_g[c] : 0.f;
        ps += acc[i] * asv;
        pd += acc[i] * adv;
    }
    ps += __shfl_xor(ps, 1); ps += __shfl_xor(ps, 2);
    pd += __shfl_xor(pd, 1); pd += __shfl_xor(pd, 2);
    if (n < N) {
#pragma unroll
        for (int i = 0; i < 5; ++i) {
            int c = c0 + i;
            if (c < 18) h2b[(size_t)n * 32 + c] = bf16of(acc[i]);
        }
        if (cq == 0) { a_s[n] = ps; a_d[n] = pd; }
    }
}

// ---- layer-2 fused, v6: h2b rows 64B-aligned (stride 32) ----
__global__ __launch_bounds__(256) void k_node_l2(const int* __restrict__ rs,
                                                 const int* __restrict__ csr,
                                                 const ushort_t* __restrict__ h2b,
                                                 const float* __restrict__ as2,
                                                 const float* __restrict__ ad2,
                                                 const float* __restrict__ b2,
                                                 float* __restrict__ out, int N) {
    __shared__ float2 stash[4][STASH_CAP];  // fast: (src,p); slow: (src,e)
    int wid = threadIdx.x >> 6;
    int lane = threadIdx.x & 63;
    int n = (blockIdx.x * 256 + threadIdx.x) >> 6;
    if (n >= N) return;
    int row = rs[n], end = rs[n + 1];
    int deg = end - row;
    float adn = ad2[n];
    int g = lane / 21;            // 0..3 (lane 63 -> g=3, acc discarded)
    int c = lane - g * 21;        // 0..20
    int cc = c < 18 ? c : 17;     // clamp for safe loads
    float acc = 0.f;
    float post;
    if (deg <= 64) {
        // ---- fast: single pass, unnormalized p; scale after group-sum ----
        bool act = lane < deg;
        int src = act ? csr[row + lane] : 0;
        float e = as2[src] + adn;
        e = e > 0.f ? e : NEG_SLOPE * e;
        if (!act) e = -INFINITY;
        float m = wmax(e);
        float p = act ? __expf(e - m) : 0.f;
        post = __builtin_amdgcn_rcpf(wsum(p));
        stash[wid][lane] = make_float2(__int_as_float(src), p);
        // 2-deep pipeline over this group's edges
        int o = g;
        for (; o + 3 < deg; o += 6) {
            float2 s0 = stash[wid][o];
            float2 s1 = stash[wid][o + 3];
            int q0 = __float_as_int(s0.x);
            int q1 = __float_as_int(s1.x);
            float v0 = bfval(h2b[(size_t)q0 * 32 + cc]);
            float v1 = bfval(h2b[(size_t)q1 * 32 + cc]);
            acc += s0.y * v0 + s1.y * v1;
        }
        if (o < deg) {
            float2 s0 = stash[wid][o];
            int q0 = __float_as_int(s0.x);
            acc += s0.y * bfval(h2b[(size_t)q0 * 32 + cc]);
        }
    } else {
        // ---- slow path (deg>64; not taken on this input) ----
        post = 1.f;
        float m = -INFINITY, l = 0.f;
        for (int base = row; base < end; base += 64) {
            int idx = base + lane;
            bool act = idx < end;
            int src = act ? csr[idx] : 0;
            float e = as2[src] + adn;
            e = e > 0.f ? e : NEG_SLOPE * e;
            int sidx = idx - row;
            if (act && sidx < STASH_CAP)
                stash[wid][sidx] = make_float2(__int_as_float(src), e);
            if (!act) e = -INFINITY;
            float mn = fmaxf(m, wmax(e));
            float p = act ? __expf(e - mn) : 0.f;
            l = l * __expf(m - mn) + wsum(p);
            m = mn;
        }
        float invl = __builtin_amdgcn_rcpf(l);
        int lim = deg < STASH_CAP ? deg : STASH_CAP;
        for (int o = g; o < lim; o += 3) {
            float2 se = stash[wid][o];
            int src = __float_as_int(se.x);
            float alpha = __expf(se.y - m) * invl;
            acc += alpha * bfval(h2b[(size_t)src * 32 + cc]);
        }
        for (int pos = row + STASH_CAP + g; pos < end; pos += 3) {
            int src = csr[pos];
            float e = as2[src] + adn;
            e = e > 0.f ? e : NEG_SLOPE * e;
            float alpha = __expf(e - m) * invl;
            acc += alpha * bfval(h2b[(size_t)src * 32 + cc]);
        }
    }
    // group-sum into lanes 0..17: both shfls read pre-mutation acc
    float t1 = __shfl(acc, (lane + 21) & 63);
    float t2 = __shfl(acc, (lane + 42) & 63);
    acc += t1 + t2;
    float bb = (lane < 18) ? b2[lane] : 0.f;
    float v = acc * post + bb;
    // ---- lane-parallel log-softmax over lanes 0..17 (32-lane xor net) ----
    float tmx = (lane < 18) ? v : -INFINITY;
    for (int o = 16; o; o >>= 1) tmx = fmaxf(tmx, __shfl_xor(tmx, o));
    float s = (lane < 18) ? __expf(v - tmx) : 0.f;
    for (int o = 16; o; o >>= 1) s += __shfl_xor(s, o);
    float lse = tmx + __logf(s);
    if (lane < 18) out[(size_t)n * 18 + lane] = v - lse;
}

extern "C" void kernel_launch(void* const* d_in, const int* in_sizes, int n_in,
                              void* d_out, int out_size, void* d_ws, size_t ws_size,
                              hipStream_t stream) {
    const float* x      = (const float*)d_in[0];
    const int*   ei     = (const int*)d_in[1];
    const float* W0     = (const float*)d_in[2];
    const float* b0     = (const float*)d_in[3];
    const float* W1     = (const float*)d_in[4];
    const float* att_s1 = (const float*)d_in[5];
    const float* att_d1 = (const float*)d_in[6];
    const float* b1     = (const float*)d_in[7];
    const float* W2     = (const float*)d_in[8];
    const float* att_s2 = (const float*)d_in[9];
    const float* att_d2 = (const float*)d_in[10];
    const float* b2     = (const float*)d_in[11];

    const int N = in_sizes[0] / 128;
    const int E = in_sizes[1] / 2;
    const int Etot = E + N;
    const int NB = (N + 1023) / 1024;  // scan blocks (<= 256)
    const int NBLK = (N + 63) / 64;    // dense tiles

    // workspace carve-up (~82 MB)
    char* w = (char*)d_ws;
    ushort_t* h1b  = (ushort_t*)w; w += (size_t)N * 128 * 2;
    unsigned* aggb = (unsigned*)w; w += (size_t)N * 128 * 2;  // bf16 x 128
    float* as1     = (float*)w;    w += (size_t)N * 2 * 4;
    float* ad1     = (float*)w;    w += (size_t)N * 2 * 4;
    ushort_t* h2b  = (ushort_t*)w; w += (size_t)N * 32 * 2;   // 64B-aligned rows
    float* as2     = (float*)w;    w += (size_t)N * 4;
    float* ad2     = (float*)w;    w += (size_t)N * 4;
    int* deg       = (int*)w;      w += (size_t)N * 4;
    int* rs        = (int*)w;      w += (size_t)(N + 1) * 4;
    int* bsum      = (int*)w;      w += (size_t)256 * 4;
    int* boff      = (int*)w;      w += (size_t)256 * 4;
    int* eofs      = (int*)w;      w += (size_t)E * 4;
    int* csr       = (int*)w;      w += (size_t)Etot * 4;

    float* out = (float*)d_out;

    // ---- CSR build (R15 form) ----
    k_deg_init<<<(N + 255) / 256, 256, 0, stream>>>(deg, N);
    k_deg_edges<<<(E + 255) / 256, 256, 0, stream>>>(ei, deg, eofs, E);
    k_scan1<<<NB, 256, 0, stream>>>(deg, rs, bsum, N);
    k_scan2<<<1, 256, 0, stream>>>(bsum, boff, NB);
    k_scan3<<<(N + 255) / 256, 256, 0, stream>>>(rs, boff, N);
    const int cohortBlocks = 128;
    k_scatter<<<8 * cohortBlocks, 256, 0, stream>>>(ei, eofs, rs, csr, E, Etot, cohortBlocks);

    // ---- fused dense front-end (256 threads) ----
    k_gemm12<<<NBLK, 256, 0, stream>>>(x, W0, b0, W1, att_s1, att_d1, h1b, as1, ad1, N);

    // ---- layer 1 fused edge pass ----
    k_node_l1<<<(N * 64 + 255) / 256, 256, 0, stream>>>(rs, csr, h1b, as1, ad1, b1, aggb, N);

    // ---- layer 2 dense + fused edge pass ----
    k_node2<<<NBLK, 256, 0, stream>>>(aggb, W2, att_s2, att_d2, h2b, as2, ad2, N);
    k_node_l2<<<(N * 64 + 255) / 256, 256, 0, stream>>>(rs, csr, h2b, as2, ad2, b2, out, N);
}